// Round 1
// baseline (963.636 us; speedup 1.0000x reference)
//
#include <hip/hip_runtime.h>
#include <cstdint>
#include <cstddef>

#define NB    8192
#define DD    768
#define NE    16
#define EDD   1536
#define KTOP  100
#define MAXT  8192

typedef __attribute__((ext_vector_type(4))) float f32x4;
typedef __attribute__((ext_vector_type(8))) short bf16x8;

__device__ __forceinline__ unsigned short f2bf(float v) {
    unsigned int u = __float_as_uint(v);
    u += 0x7FFFu + ((u >> 16) & 1u);   // RNE to bf16
    return (unsigned short)(u >> 16);
}
__device__ __forceinline__ float bf2f(unsigned short h) {
    return __uint_as_float(((unsigned int)h) << 16);
}

// ---------------------------------------------------------------- K1: gate
// one wave per token; fp64 logits/softmax/renorm; builds per-expert lists.
__global__ __launch_bounds__(256) void k1_gate(
    const float* __restrict__ x, const float* __restrict__ gate_W,
    const float* __restrict__ gate_b, const float* __restrict__ b_gate,
    int* __restrict__ eids, double* __restrict__ entw,
    int* __restrict__ counts, int* __restrict__ lists)
{
    const int wid  = threadIdx.x >> 6;
    const int lane = threadIdx.x & 63;
    const int tok  = blockIdx.x * 4 + wid;

    double xv[12];
#pragma unroll
    for (int j = 0; j < 12; ++j) {
        const int k = j * 64 + lane;
        xv[j] = (double)x[(size_t)tok * DD + k] - (double)b_gate[k];
    }

    double myLogit = -1.0e300;
    for (int e = 0; e < NE; ++e) {
        double d = 0.0;
#pragma unroll
        for (int j = 0; j < 12; ++j)
            d += xv[j] * (double)gate_W[e * DD + j * 64 + lane];
#pragma unroll
        for (int off = 32; off > 0; off >>= 1)
            d += __shfl_xor(d, off);
        if (lane == e) myLogit = d + (double)gate_b[e];
    }

    // softmax over the 16 lanes holding logits (xor masks < 16 stay in-group)
    double m = myLogit;
#pragma unroll
    for (int off = 8; off > 0; off >>= 1) {
        double o = __shfl_xor(m, off); m = (o > m) ? o : m;
    }
    double p = exp(myLogit - m);
    double ssum = p;
#pragma unroll
    for (int off = 8; off > 0; off >>= 1) ssum += __shfl_xor(ssum, off);
    const double score = p / ssum;

    const bool lt16 = (lane < NE);
    double m1 = score;
#pragma unroll
    for (int off = 8; off > 0; off >>= 1) {
        double o = __shfl_xor(m1, off); m1 = (o > m1) ? o : m1;
    }
    unsigned long long b0 = __ballot(lt16 && (score == m1));
    const int i0 = __ffsll(b0) - 1;
    double sc2 = (lane == i0) ? -1.0 : score;
    double m2 = sc2;
#pragma unroll
    for (int off = 8; off > 0; off >>= 1) {
        double o = __shfl_xor(m2, off); m2 = (o > m2) ? o : m2;
    }
    unsigned long long b1 = __ballot(lt16 && (sc2 == m2));
    const int i1 = __ffsll(b1) - 1;

    if (lane == 0) {
        const double w0 = 1.0 / (1.0 + exp(m2 - m1));  // softmax([s0,s1])
        const double w1 = 1.0 - w0;
        eids[tok * 2 + 0] = i0;
        eids[tok * 2 + 1] = i1;
        entw[tok * 2 + 0] = w0;
        entw[tok * 2 + 1] = w1;
        const int p0 = atomicAdd(&counts[i0], 1);
        lists[i0 * MAXT + p0] = tok * 2;
        const int p1 = atomicAdd(&counts[i1], 1);
        lists[i1 * MAXT + p1] = tok * 2 + 1;
    }
}

// ------------------------------------------------- K2: grouped expert GEMM
// 128x128 tile, BK=64, split-bf16 (hh+hl+lh) MFMA 16x16x32, fused
// bias+relu+renorm, scatter rows to f[entry][1536].
__global__ __launch_bounds__(256, 2) void k2_encode(
    const float* __restrict__ x, const float* __restrict__ b_dec,
    const float* __restrict__ expert_W, const float* __restrict__ expert_b,
    const int* __restrict__ counts, const int* __restrict__ lists,
    const double* __restrict__ entw, float* __restrict__ fbuf)
{
    const int e = blockIdx.z;
    const int cnt = counts[e];
    const int mbase = blockIdx.y * 128;
    if (mbase >= cnt) return;
    const int rows = min(128, cnt - mbase);
    const int nbase = blockIdx.x * 128;

    __shared__ char smem[65536];
    char* Ahi = smem;
    char* Alo = smem + 16384;
    char* Bhi = smem + 32768;
    char* Blo = smem + 49152;

    const int t = threadIdx.x;
    const int lane = t & 63;
    const int wid = t >> 6;
    const int wm = wid >> 1, wn = wid & 1;
    const int l15 = lane & 15, q = lane >> 4;

    // staging map: 16 k-quads x 16 row-groups (8 rows each)
    const int kq = t & 15, rg = t >> 4;

    int tok_r[8];
#pragma unroll
    for (int j = 0; j < 8; ++j) {
        const int r = rg * 8 + j;
        const int ent = (r < rows) ? lists[e * MAXT + mbase + r] : -1;
        tok_r[j] = (ent >= 0) ? (ent >> 1) : -1;
    }

    f32x4 acc[4][4];
#pragma unroll
    for (int a = 0; a < 4; ++a)
#pragma unroll
        for (int b = 0; b < 4; ++b)
            acc[a][b] = f32x4{0.f, 0.f, 0.f, 0.f};

    for (int s = 0; s < 12; ++s) {
        const float4 bd4 = *reinterpret_cast<const float4*>(b_dec + s * 64 + kq * 4);
#pragma unroll
        for (int j = 0; j < 8; ++j) {
            const int r = rg * 8 + j;
            float4 av = make_float4(0.f, 0.f, 0.f, 0.f);
            const int tok = tok_r[j];
            if (tok >= 0) {
                av = *reinterpret_cast<const float4*>(x + (size_t)tok * DD + s * 64 + kq * 4);
                av.x -= bd4.x; av.y -= bd4.y; av.z -= bd4.z; av.w -= bd4.w;
            }
            const float4 bv = *reinterpret_cast<const float4*>(
                expert_W + ((size_t)e * EDD + nbase + r) * DD + s * 64 + kq * 4);
            const int boff = (r * 128 + kq * 8) ^ ((r & 7) << 4);
            ushort4 ah4, al4, bh4, bl4;
            {
                unsigned short h;
                h = f2bf(av.x); ah4.x = h; al4.x = f2bf(av.x - bf2f(h));
                h = f2bf(av.y); ah4.y = h; al4.y = f2bf(av.y - bf2f(h));
                h = f2bf(av.z); ah4.z = h; al4.z = f2bf(av.z - bf2f(h));
                h = f2bf(av.w); ah4.w = h; al4.w = f2bf(av.w - bf2f(h));
                h = f2bf(bv.x); bh4.x = h; bl4.x = f2bf(bv.x - bf2f(h));
                h = f2bf(bv.y); bh4.y = h; bl4.y = f2bf(bv.y - bf2f(h));
                h = f2bf(bv.z); bh4.z = h; bl4.z = f2bf(bv.z - bf2f(h));
                h = f2bf(bv.w); bh4.w = h; bl4.w = f2bf(bv.w - bf2f(h));
            }
            *reinterpret_cast<ushort4*>(Ahi + boff) = ah4;
            *reinterpret_cast<ushort4*>(Alo + boff) = al4;
            *reinterpret_cast<ushort4*>(Bhi + boff) = bh4;
            *reinterpret_cast<ushort4*>(Blo + boff) = bl4;
        }
        __syncthreads();

#pragma unroll
        for (int ks = 0; ks < 2; ++ks) {
            bf16x8 ah[4], al[4], bh[4], bl[4];
#pragma unroll
            for (int fm = 0; fm < 4; ++fm) {
                const int row = wm * 64 + fm * 16 + l15;
                const int boff = (row * 128 + ks * 64 + q * 16) ^ ((row & 7) << 4);
                ah[fm] = *reinterpret_cast<const bf16x8*>(Ahi + boff);
                al[fm] = *reinterpret_cast<const bf16x8*>(Alo + boff);
            }
#pragma unroll
            for (int fn = 0; fn < 4; ++fn) {
                const int row = wn * 64 + fn * 16 + l15;
                const int boff = (row * 128 + ks * 64 + q * 16) ^ ((row & 7) << 4);
                bh[fn] = *reinterpret_cast<const bf16x8*>(Bhi + boff);
                bl[fn] = *reinterpret_cast<const bf16x8*>(Blo + boff);
            }
#pragma unroll
            for (int fm = 0; fm < 4; ++fm)
#pragma unroll
                for (int fn = 0; fn < 4; ++fn) {
                    acc[fm][fn] = __builtin_amdgcn_mfma_f32_16x16x32_bf16(ah[fm], bh[fn], acc[fm][fn], 0, 0, 0);
                    acc[fm][fn] = __builtin_amdgcn_mfma_f32_16x16x32_bf16(ah[fm], bl[fn], acc[fm][fn], 0, 0, 0);
                    acc[fm][fn] = __builtin_amdgcn_mfma_f32_16x16x32_bf16(al[fm], bh[fn], acc[fm][fn], 0, 0, 0);
                }
        }
        __syncthreads();
    }

    // epilogue: C/D layout col=lane&15, row=(lane>>4)*4+reg
#pragma unroll
    for (int fm = 0; fm < 4; ++fm) {
#pragma unroll
        for (int r = 0; r < 4; ++r) {
            const int ml = wm * 64 + fm * 16 + q * 4 + r;
            if (ml >= rows) continue;
            const int ent = lists[e * MAXT + mbase + ml];
            const float ren = (float)entw[ent];
            float* fout = fbuf + (size_t)ent * EDD + nbase;
#pragma unroll
            for (int fn = 0; fn < 4; ++fn) {
                const int nl = wn * 64 + fn * 16 + l15;
                float v = acc[fm][fn][r] + expert_b[e * EDD + nbase + nl];
                v = fmaxf(v, 0.f) * ren;
                fout[nl] = v;
            }
        }
    }
}

// --------------------------- K3: per-token exact top-100 + fused decode
__global__ __launch_bounds__(256) void k3_topk_decode(
    const float* __restrict__ x, const float* __restrict__ b_dec,
    const float* __restrict__ expert_W, const float* __restrict__ expert_b,
    const int* __restrict__ eids, const double* __restrict__ entw,
    const float* __restrict__ fbuf, const float* __restrict__ decoder,
    float* __restrict__ out)
{
    const int tok = blockIdx.x;
    const int t = threadIdx.x;

    __shared__ float fv[3072];
    __shared__ unsigned int hist[256];
    __shared__ unsigned int prefix_s;
    __shared__ int remaining_s, tz_s;
    __shared__ int nsel_s, ncand_s, total_s;
    __shared__ int   sel_didx[KTOP];
    __shared__ float sel_act[KTOP];
    __shared__ int    cidx[64];
    __shared__ double cval[64];
    __shared__ double dred[256];

    const float* frow = fbuf + (size_t)tok * 2 * EDD;
#pragma unroll
    for (int i = 0; i < 12; ++i) fv[t + 256 * i] = frow[t + 256 * i];
    if (t == 0) { prefix_s = 0u; remaining_s = KTOP; tz_s = 0; nsel_s = 0; ncand_s = 0; }
    __syncthreads();

    // 4-pass radix select (MSB->LSB) for exact 100th-largest fp32 value
    for (int p = 0; p < 4; ++p) {
        hist[t] = 0u;
        __syncthreads();
        const unsigned int pref = prefix_s;
        const int shift = 24 - 8 * p;
        const unsigned int maskhi = (p == 0) ? 0u : (0xFFFFFFFFu << (shift + 8));
        for (int i = 0; i < 12; ++i) {
            const unsigned int u = __float_as_uint(fv[t + 256 * i]);
            if (u != 0u && (u & maskhi) == pref)
                atomicAdd(&hist[(u >> shift) & 255u], 1u);
        }
        __syncthreads();
        if (t == 0) {
            const int rem = remaining_s;
            unsigned int cum = 0u;
            int v = 255;
            for (; v >= 0; --v) {
                const unsigned int c = hist[v];
                if (cum + c >= (unsigned int)rem) break;
                cum += c;
            }
            if (v < 0) tz_s = 1;   // fewer than 100 positives
            else {
                prefix_s = pref | ((unsigned int)v << shift);
                remaining_s = rem - (int)cum;
            }
        }
        __syncthreads();
        if (tz_s) break;
    }

    if (tz_s) {
        // take all positives (acts beyond them are exact zeros -> no contribution)
        for (int i = 0; i < 12; ++i) {
            const int j = t + 256 * i;
            const float v = fv[j];
            if (v > 0.f) {
                const int pz = atomicAdd(&nsel_s, 1);
                const int slot = (j >= EDD) ? 1 : 0;
                const int n = j - slot * EDD;
                sel_didx[pz] = eids[tok * 2 + slot] * EDD + n;
                sel_act[pz] = v;
            }
        }
        __syncthreads();
        if (t == 0) total_s = nsel_s;
        __syncthreads();
    } else {
        const float T = __uint_as_float(prefix_s);
        const float W = T * 2e-4f + 1e-6f;       // >> bulk error (~3e-6), << gap scale
        const float vhi = T + W, vlo = T - W;
        for (int i = 0; i < 12; ++i) {
            const int j = t + 256 * i;
            const float v = fv[j];
            if (v > vhi) {
                const int pz = atomicAdd(&nsel_s, 1);
                const int slot = (j >= EDD) ? 1 : 0;
                const int n = j - slot * EDD;
                sel_didx[pz] = eids[tok * 2 + slot] * EDD + n;
                sel_act[pz] = v;
            } else if (v >= vlo) {
                const int c = atomicAdd(&ncand_s, 1);
                if (c < 64) cidx[c] = j;
            }
        }
        __syncthreads();
        const int ncand = min(ncand_s, 64);
        // fp64 re-evaluation of boundary candidates
        for (int c = 0; c < ncand; ++c) {
            const int j = cidx[c];
            const int slot = (j >= EDD) ? 1 : 0;
            const int n = j - slot * EDD;
            const int ee = eids[tok * 2 + slot];
            const float* wrow = expert_W + ((size_t)ee * EDD + n) * DD;
            const float* xrow = x + (size_t)tok * DD;
            double part = 0.0;
#pragma unroll
            for (int i = 0; i < 3; ++i) {
                const int k = t + 256 * i;
                part += ((double)xrow[k] - (double)b_dec[k]) * (double)wrow[k];
            }
            dred[t] = part;
            __syncthreads();
            for (int off = 128; off > 0; off >>= 1) {
                if (t < off) dred[t] += dred[t + off];
                __syncthreads();
            }
            if (t == 0) {
                double z = dred[0] + (double)expert_b[ee * EDD + n];
                if (z < 0.0) z = 0.0;
                cval[c] = z * entw[tok * 2 + slot];
            }
            __syncthreads();
        }
        if (t == 0) {
            const int nsel = nsel_s;
            int need = KTOP - nsel;
            if (need > ncand) need = ncand;
            for (int c = 0; c < need; ++c) {   // (value desc, dict idx asc)
                double bv = -1.0; int bdi = 0x7FFFFFFF; int bi = -1;
                for (int i = 0; i < ncand; ++i) {
                    const int j = cidx[i];
                    if (j < 0) continue;
                    const int slot = (j >= EDD) ? 1 : 0;
                    const int n = j - slot * EDD;
                    const int di = eids[tok * 2 + slot] * EDD + n;
                    const double v = cval[i];
                    if (v > bv || (v == bv && di < bdi)) { bv = v; bdi = di; bi = i; }
                }
                cidx[bi] = -1;
                sel_didx[nsel + c] = bdi;
                sel_act[nsel + c] = (float)bv;
            }
            total_s = nsel + need;
        }
        __syncthreads();
    }

    // fused decode: x_hat = sum a_k * decoder[idx_k] + b_dec
    const int total = total_s;
    float a0 = 0.f, a1 = 0.f, a2 = 0.f;
    for (int k = 0; k < total; ++k) {
        const float a = sel_act[k];
        const float* drow = decoder + (size_t)sel_didx[k] * DD;
        a0 += a * drow[t];
        a1 += a * drow[t + 256];
        a2 += a * drow[t + 512];
    }
    out[(size_t)tok * DD + t]       = a0 + b_dec[t];
    out[(size_t)tok * DD + t + 256] = a1 + b_dec[t + 256];
    out[(size_t)tok * DD + t + 512] = a2 + b_dec[t + 512];
}

// sentinel fill if workspace is too small (diagnosable: absmax ~ 12345)
__global__ void k_sentinel(float* __restrict__ out, int n) {
    int i = blockIdx.x * blockDim.x + threadIdx.x;
    if (i < n) out[i] = 12345.0f;
}

extern "C" void kernel_launch(void* const* d_in, const int* in_sizes, int n_in,
                              void* d_out, int out_size, void* d_ws, size_t ws_size,
                              hipStream_t stream)
{
    (void)in_sizes; (void)n_in;
    const float* x        = (const float*)d_in[0];
    const float* gate_W   = (const float*)d_in[1];
    const float* gate_b   = (const float*)d_in[2];
    const float* b_gate   = (const float*)d_in[3];
    const float* b_dec    = (const float*)d_in[4];
    const float* expert_W = (const float*)d_in[5];
    const float* expert_b = (const float*)d_in[6];
    const float* decoder  = (const float*)d_in[7];
    float* out = (float*)d_out;

    char* ws = (char*)d_ws;
    // layout: counts(256) | lists(16*8192*4) | entw(16384*8) | eids(16384*4) | f(16384*1536*4)
    const size_t off_lists = 256;
    const size_t off_entw  = off_lists + (size_t)NE * MAXT * 4;      // 524544
    const size_t off_eids  = off_entw + (size_t)NB * 2 * 8;          // 655616
    const size_t off_f     = off_eids + (size_t)NB * 2 * 4;          // 721152
    const size_t need      = off_f + (size_t)NB * 2 * EDD * 4;       // ~101.4 MB

    if (ws_size < need) {
        k_sentinel<<<(out_size + 255) / 256, 256, 0, stream>>>(out, out_size);
        return;
    }

    int*    counts = (int*)ws;
    int*    lists  = (int*)(ws + off_lists);
    double* entw   = (double*)(ws + off_entw);
    int*    eids   = (int*)(ws + off_eids);
    float*  fbuf   = (float*)(ws + off_f);

    hipMemsetAsync(counts, 0, 64, stream);
    k1_gate<<<NB / 4, 256, 0, stream>>>(x, gate_W, gate_b, b_gate, eids, entw, counts, lists);
    dim3 g2(EDD / 128, MAXT / 128, NE);   // (12, 64, 16), early-exit on count
    k2_encode<<<g2, 256, 0, stream>>>(x, b_dec, expert_W, expert_b, counts, lists, entw, fbuf);
    k3_topk_decode<<<NB, 256, 0, stream>>>(x, b_dec, expert_W, expert_b, eids, entw, fbuf, decoder, out);
}